// Round 6
// baseline (542.978 us; speedup 1.0000x reference)
//
#include <hip/hip_runtime.h>
#include <hip/hip_bf16.h>

// CFConv, round 5. Two-pass streaming:
//   Pass A (natural edge order, TILE=32, ~31KB LDS -> 4 blocks/CU):
//     msg[e] = bf16( h[col[e]] * (relu(rbf[e]@W1+b1)@W2+b2) )  (coalesced)
//   Pass B: out[n] = sum_{i in [row_ptr[n],row_ptr[n+1])} msg[perm[i]]
//     (wave per node, uint4 gather = 4 rows/load, shfl_xor combine)
// Sort: hist + 1-block scan + scatter(perm). 7 dispatches total.

#define N_NODES 40000
#define N_EDGES 640000
#define IN_CH 128
#define OUT_CH 128
#define NUM_RBF 64

#define TILE_M 32
#define NTILES (N_EDGES / TILE_M)  // 20000 exact
#define RBF_STR 72   // ushorts (144B rows, 16B aligned)
#define T_STR 136    // ushorts (272B rows, 16B aligned)
#define HV_STR 136
#define MSG_STR 136
#define W1_STR 72
#define W2_STR 136
#define NL_TILE 64   // node_linear rows/block

typedef __attribute__((ext_vector_type(8))) short bf16x8;
typedef __attribute__((ext_vector_type(16))) float f32x16;

__device__ __forceinline__ unsigned short f2bf(float f) {
  unsigned u = __float_as_uint(f);
  return (unsigned short)((u + 0x7FFFu + ((u >> 16) & 1u)) >> 16);
}
__device__ __forceinline__ float bf2f(unsigned short s) {
  return __uint_as_float(((unsigned)s) << 16);
}

// ---------------------------------------------------------------------------
// h = bf16(x @ Wl + bl)
// ---------------------------------------------------------------------------
__global__ __launch_bounds__(256) void node_linear_mfma(
    const float* __restrict__ x, const float* __restrict__ Wl,
    const float* __restrict__ bl, unsigned short* __restrict__ hbf) {
  __shared__ __align__(16) char pool[IN_CH * W2_STR * 2];  // 34816 B
  const int t = threadIdx.x;
  const int lane = t & 63;
  const int l31 = lane & 31;
  const int lhalf = lane >> 5;
  const int wv = t >> 6;

  {
    unsigned short* sWT = (unsigned short*)pool;
    const int k2 = t >> 1;
    const int d0 = (t & 1) * 64;
#pragma unroll
    for (int i = 0; i < 16; ++i) {
      float4 v = *(const float4*)(Wl + k2 * OUT_CH + d0 + 4 * i);
      sWT[(d0 + 4 * i + 0) * W2_STR + k2] = f2bf(v.x);
      sWT[(d0 + 4 * i + 1) * W2_STR + k2] = f2bf(v.y);
      sWT[(d0 + 4 * i + 2) * W2_STR + k2] = f2bf(v.z);
      sWT[(d0 + 4 * i + 3) * W2_STR + k2] = f2bf(v.w);
    }
  }
  __syncthreads();
  const int nbase = wv * 32 + l31;
  bf16x8 BW[8];
  {
    const unsigned short* sWT = (const unsigned short*)pool;
#pragma unroll
    for (int kk = 0; kk < 8; ++kk)
      BW[kk] = *(const bf16x8*)&sWT[nbase * W2_STR + kk * 16 + lhalf * 8];
  }
  const float blv = bl[nbase];
  __syncthreads();

  const int rbase = blockIdx.x * NL_TILE;
  unsigned short* sX = (unsigned short*)pool;
  {
    const int m = t >> 2;
    const int c0 = (t & 3) * 32;
    const float* src = x + (size_t)(rbase + m) * IN_CH + c0;
#pragma unroll
    for (int i = 0; i < 8; ++i) {
      float4 v = *(const float4*)(src + 4 * i);
      ushort4 p;
      p.x = f2bf(v.x); p.y = f2bf(v.y); p.z = f2bf(v.z); p.w = f2bf(v.w);
      *(ushort4*)&sX[m * T_STR + c0 + 4 * i] = p;
    }
  }
  __syncthreads();
#pragma unroll
  for (int mt = 0; mt < 2; ++mt) {
    f32x16 acc = {0.f, 0.f, 0.f, 0.f, 0.f, 0.f, 0.f, 0.f,
                  0.f, 0.f, 0.f, 0.f, 0.f, 0.f, 0.f, 0.f};
#pragma unroll
    for (int kk = 0; kk < 8; ++kk) {
      bf16x8 A = *(const bf16x8*)&sX[(mt * 32 + l31) * T_STR + kk * 16 + lhalf * 8];
      acc = __builtin_amdgcn_mfma_f32_32x32x16_bf16(A, BW[kk], acc, 0, 0, 0);
    }
#pragma unroll
    for (int r = 0; r < 16; ++r) {
      const int rowm = mt * 32 + (r & 3) + 8 * (r >> 2) + 4 * lhalf;
      hbf[(size_t)(rbase + rowm) * OUT_CH + nbase] = f2bf(acc[r] + blv);
    }
  }
}

// ---------------------------------------------------------------------------
// counting sort by dst -> perm (sorted->orig edge id), row_ptr
// ---------------------------------------------------------------------------
__global__ void hist_kernel(const int* __restrict__ rowI, int* __restrict__ count) {
  int e = blockIdx.x * 256 + threadIdx.x;
  if (e < N_EDGES) atomicAdd(&count[rowI[e]], 1);
}

__global__ __launch_bounds__(1024) void scan_kernel(const int* __restrict__ count,
                                                    int* __restrict__ cursor,
                                                    int* __restrict__ row_ptr) {
  __shared__ int sSum[1024];
  const int t = threadIdx.x;
  const int per = (N_NODES + 1023) / 1024;  // 40
  const int base = t * per;
  int s = 0;
  for (int i = 0; i < per; ++i) {
    int idx = base + i;
    if (idx < N_NODES) s += count[idx];
  }
  sSum[t] = s;
  __syncthreads();
  for (int off = 1; off < 1024; off <<= 1) {
    int v = (t >= off) ? sSum[t - off] : 0;
    __syncthreads();
    sSum[t] += v;
    __syncthreads();
  }
  int run = (t == 0) ? 0 : sSum[t - 1];
  for (int i = 0; i < per; ++i) {
    int idx = base + i;
    if (idx < N_NODES) {
      cursor[idx] = run;
      row_ptr[idx] = run;
      run += count[idx];
    }
  }
  if (t == 0) row_ptr[N_NODES] = N_EDGES;
}

__global__ void scatter_kernel(const int* __restrict__ rowI, int* __restrict__ cursor,
                               int* __restrict__ perm) {
  int e = blockIdx.x * 256 + threadIdx.x;
  if (e < N_EDGES) {
    int pos = atomicAdd(&cursor[rowI[e]], 1);
    perm[pos] = e;
  }
}

// ---------------------------------------------------------------------------
// Pass A: filter + modulate, natural edge order, coalesced msg writes.
//   ATOMIC=true fallback: atomicAdd into out directly.
// ---------------------------------------------------------------------------
template <bool ATOMIC>
__global__ __launch_bounds__(256, 4) void edge_filter_kernel(
    const int* __restrict__ eidx, const float* __restrict__ rbf,
    const float* __restrict__ W1, const float* __restrict__ b1,
    const float* __restrict__ W2, const float* __restrict__ b2,
    const unsigned short* __restrict__ hbf,
    unsigned short* __restrict__ msg, float* __restrict__ outp) {
  __shared__ __align__(16) char pool[22016];
  __shared__ __align__(16) unsigned short sHv[TILE_M * HV_STR];  // 8704 B
  unsigned short* sT = (unsigned short*)pool;                    // 8704 B
  unsigned short* sMsg = (unsigned short*)(pool + 8704);         // 8704 B
  unsigned short* sRbf = (unsigned short*)(pool + 17408);        // 4608 B

  const int t = threadIdx.x;
  const int lane = t & 63;
  const int l31 = lane & 31;
  const int lhalf = lane >> 5;
  const int wv = t >> 6;
  const int nbase = wv * 32 + l31;

  // ---- W1 full staging into pool ----
  {
    unsigned short* sW1T = (unsigned short*)pool;  // [128][W1_STR] = 18432 B
    const int k = t >> 2;            // 0..63
    const int c0 = (t & 3) * 32;
#pragma unroll
    for (int i = 0; i < 8; ++i) {
      float4 v = *(const float4*)(W1 + k * OUT_CH + c0 + 4 * i);
      sW1T[(c0 + 4 * i + 0) * W1_STR + k] = f2bf(v.x);
      sW1T[(c0 + 4 * i + 1) * W1_STR + k] = f2bf(v.y);
      sW1T[(c0 + 4 * i + 2) * W1_STR + k] = f2bf(v.z);
      sW1T[(c0 + 4 * i + 3) * W1_STR + k] = f2bf(v.w);
    }
  }
  __syncthreads();
  bf16x8 B1[4];
  {
    const unsigned short* sW1T = (const unsigned short*)pool;
#pragma unroll
    for (int kk = 0; kk < 4; ++kk)
      B1[kk] = *(const bf16x8*)&sW1T[nbase * W1_STR + kk * 16 + lhalf * 8];
  }
  __syncthreads();

  // ---- W2 staged in two d-halves (pool = 64 x W2_STR = 17408 B) ----
  bf16x8 B2[8];
#pragma unroll
  for (int hd = 0; hd < 2; ++hd) {
    {
      unsigned short* sW2T = (unsigned short*)pool;
      const int k2 = t >> 1;            // 0..127
      const int d0 = (t & 1) * 32;      // local d base
#pragma unroll
      for (int i = 0; i < 8; ++i) {
        float4 v = *(const float4*)(W2 + k2 * OUT_CH + hd * 64 + d0 + 4 * i);
        sW2T[(d0 + 4 * i + 0) * W2_STR + k2] = f2bf(v.x);
        sW2T[(d0 + 4 * i + 1) * W2_STR + k2] = f2bf(v.y);
        sW2T[(d0 + 4 * i + 2) * W2_STR + k2] = f2bf(v.z);
        sW2T[(d0 + 4 * i + 3) * W2_STR + k2] = f2bf(v.w);
      }
    }
    __syncthreads();
    if ((wv >> 1) == hd) {
      const unsigned short* sW2T = (const unsigned short*)pool;
      const int dl = nbase & 63;
#pragma unroll
      for (int kk = 0; kk < 8; ++kk)
        B2[kk] = *(const bf16x8*)&sW2T[dl * W2_STR + kk * 16 + lhalf * 8];
    }
    __syncthreads();
  }
  const float b1v = b1[nbase];
  const float b2v = b2[nbase];

  const int* rowI = eidx;
  const int* colI = eidx + N_EDGES;

  for (int tile = blockIdx.x; tile < NTILES; tile += gridDim.x) {
    const int ebase = tile * TILE_M;

    // ---- stage rbf (fp32->bf16) + gathered hbf rows ----
    {
      const int m8 = t >> 3;           // row 0..31
      const int sg = t & 7;            // 8-float segment
      const float* src = rbf + (size_t)(ebase + m8) * NUM_RBF + sg * 8;
      float4 v0 = *(const float4*)src;
      float4 v1 = *(const float4*)(src + 4);
      uint4 p;
      p.x = (unsigned)f2bf(v0.x) | ((unsigned)f2bf(v0.y) << 16);
      p.y = (unsigned)f2bf(v0.z) | ((unsigned)f2bf(v0.w) << 16);
      p.z = (unsigned)f2bf(v1.x) | ((unsigned)f2bf(v1.y) << 16);
      p.w = (unsigned)f2bf(v1.z) | ((unsigned)f2bf(v1.w) << 16);
      *(uint4*)&sRbf[m8 * RBF_STR + sg * 8] = p;
#pragma unroll
      for (int i = 0; i < 2; ++i) {
        const int chunk = t + 256 * i;          // 512 chunks = 32 rows x 16
        const int rw = chunk >> 4;
        const int cc = chunk & 15;
        const int col = colI[ebase + rw];
        *(uint4*)&sHv[rw * HV_STR + cc * 8] =
            *((const uint4*)(hbf + (size_t)col * OUT_CH) + cc);
      }
    }
    __syncthreads();  // (b)

    // ---- GEMM1: sT = bf16(relu(rbf @ W1 + b1)), M=32 ----
    {
      f32x16 acc = {0.f, 0.f, 0.f, 0.f, 0.f, 0.f, 0.f, 0.f,
                    0.f, 0.f, 0.f, 0.f, 0.f, 0.f, 0.f, 0.f};
#pragma unroll
      for (int kk = 0; kk < 4; ++kk) {
        bf16x8 A = *(const bf16x8*)&sRbf[l31 * RBF_STR + kk * 16 + lhalf * 8];
        acc = __builtin_amdgcn_mfma_f32_32x32x16_bf16(A, B1[kk], acc, 0, 0, 0);
      }
#pragma unroll
      for (int r = 0; r < 16; ++r) {
        const int rowm = (r & 3) + 8 * (r >> 2) + 4 * lhalf;
        float v = acc[r] + b1v;
        v = v > 0.f ? v : 0.f;
        sT[rowm * T_STR + nbase] = f2bf(v);
      }
    }
    __syncthreads();  // (c)

    // ---- GEMM2 + modulate (hv read inline from LDS) ----
    {
      f32x16 acc = {0.f, 0.f, 0.f, 0.f, 0.f, 0.f, 0.f, 0.f,
                    0.f, 0.f, 0.f, 0.f, 0.f, 0.f, 0.f, 0.f};
#pragma unroll
      for (int kk = 0; kk < 8; ++kk) {
        bf16x8 A = *(const bf16x8*)&sT[l31 * T_STR + kk * 16 + lhalf * 8];
        acc = __builtin_amdgcn_mfma_f32_32x32x16_bf16(A, B2[kk], acc, 0, 0, 0);
      }
#pragma unroll
      for (int r = 0; r < 16; ++r) {
        const int rowm = (r & 3) + 8 * (r >> 2) + 4 * lhalf;
        const float m = bf2f(sHv[rowm * HV_STR + nbase]) * (acc[r] + b2v);
        if (ATOMIC) {
          atomicAdd(&outp[(size_t)rowI[ebase + rowm] * OUT_CH + nbase], m);
        } else {
          sMsg[rowm * MSG_STR + nbase] = f2bf(m);
        }
      }
    }

    __syncthreads();  // (d)
    if (!ATOMIC) {
      // coalesced natural-order store: 32 rows x 256B
      const int m = t >> 3;
      const unsigned short* srcr = &sMsg[m * MSG_STR];
      uint4* dst = (uint4*)(msg + (size_t)(ebase + m) * OUT_CH);
#pragma unroll
      for (int i = 0; i < 2; ++i) {
        const int cc = (t & 7) + 8 * i;
        dst[cc] = *(const uint4*)(srcr + cc * 8);
      }
    }
  }
}

// ---------------------------------------------------------------------------
// Pass B: wave per node; gather msg rows via perm, 4 rows per uint4 load.
// ---------------------------------------------------------------------------
__global__ __launch_bounds__(256) void segment_reduce_kernel(
    const unsigned short* __restrict__ msg, const int* __restrict__ perm,
    const int* __restrict__ row_ptr, float* __restrict__ out) {
  const int t = threadIdx.x;
  const int wv = t >> 6;
  const int lane = t & 63;
  const int n = blockIdx.x * 4 + wv;
  const int ebeg = row_ptr[n];
  const int eend = row_ptr[n + 1];
  const int sub = lane >> 4;    // row-within-quad
  const int cidx = lane & 15;   // 16B column chunk
  const uint4* p = (const uint4*)msg;  // row = 16 uint4

  float a0 = 0.f, a1 = 0.f, a2 = 0.f, a3 = 0.f;
  float a4 = 0.f, a5 = 0.f, a6 = 0.f, a7 = 0.f;
  for (int e = ebeg; e < eend; e += 4) {
    const int r = e + sub;
    const int valid = r < eend;
    const int pr = perm[valid ? r : ebeg];
    uint4 v = p[(size_t)pr * 16 + cidx];
    if (valid) {
      a0 += bf2f((unsigned short)(v.x & 0xffff));
      a1 += bf2f((unsigned short)(v.x >> 16));
      a2 += bf2f((unsigned short)(v.y & 0xffff));
      a3 += bf2f((unsigned short)(v.y >> 16));
      a4 += bf2f((unsigned short)(v.z & 0xffff));
      a5 += bf2f((unsigned short)(v.z >> 16));
      a6 += bf2f((unsigned short)(v.w & 0xffff));
      a7 += bf2f((unsigned short)(v.w >> 16));
    }
  }
  a0 += __shfl_xor(a0, 16); a1 += __shfl_xor(a1, 16);
  a2 += __shfl_xor(a2, 16); a3 += __shfl_xor(a3, 16);
  a4 += __shfl_xor(a4, 16); a5 += __shfl_xor(a5, 16);
  a6 += __shfl_xor(a6, 16); a7 += __shfl_xor(a7, 16);
  a0 += __shfl_xor(a0, 32); a1 += __shfl_xor(a1, 32);
  a2 += __shfl_xor(a2, 32); a3 += __shfl_xor(a3, 32);
  a4 += __shfl_xor(a4, 32); a5 += __shfl_xor(a5, 32);
  a6 += __shfl_xor(a6, 32); a7 += __shfl_xor(a7, 32);
  if (sub == 0) {
    float* dst = out + (size_t)n * OUT_CH + cidx * 8;
    float4 o0; o0.x = a0; o0.y = a1; o0.z = a2; o0.w = a3;
    float4 o1; o1.x = a4; o1.y = a5; o1.z = a6; o1.w = a7;
    *(float4*)dst = o0;
    *(float4*)(dst + 4) = o1;
  }
}

// ---------------------------------------------------------------------------
extern "C" void kernel_launch(void* const* d_in, const int* in_sizes, int n_in,
                              void* d_out, int out_size, void* d_ws, size_t ws_size,
                              hipStream_t stream) {
  const float* x    = (const float*)d_in[0];
  const int*   eidx = (const int*)d_in[1];
  const float* rbf  = (const float*)d_in[2];
  const float* W1   = (const float*)d_in[3];
  const float* b1   = (const float*)d_in[4];
  const float* W2   = (const float*)d_in[5];
  const float* b2   = (const float*)d_in[6];
  const float* Wl   = (const float*)d_in[7];
  const float* bl   = (const float*)d_in[8];
  float* out = (float*)d_out;

  char* ws = (char*)d_ws;
  const size_t HBF_B = (size_t)N_NODES * OUT_CH * 2;   // 10,240,000
  const size_t MSG_B = (size_t)N_EDGES * OUT_CH * 2;   // 163,840,000
  const size_t PERM_B = (size_t)N_EDGES * 4;           //   2,560,000
  const size_t CNT_B = (size_t)N_NODES * 4;            //     160,000
  const size_t RP_B = CNT_B + 16;
  const size_t need = HBF_B + MSG_B + PERM_B + 2 * CNT_B + RP_B + 64;

  size_t off = 0;
  unsigned short* hbf = (unsigned short*)(ws + off); off += HBF_B;
  unsigned short* msg = (unsigned short*)(ws + off); off += MSG_B;
  int* perm    = (int*)(ws + off); off += PERM_B;
  int* count   = (int*)(ws + off); off += CNT_B;
  int* cursor  = (int*)(ws + off); off += CNT_B;
  int* row_ptr = (int*)(ws + off); off += RP_B;

  node_linear_mfma<<<N_NODES / NL_TILE, 256, 0, stream>>>(x, Wl, bl, hbf);

  if (ws_size >= need) {
    hipMemsetAsync(count, 0, CNT_B, stream);
    hist_kernel<<<(N_EDGES + 255) / 256, 256, 0, stream>>>(eidx, count);
    scan_kernel<<<1, 1024, 0, stream>>>(count, cursor, row_ptr);
    scatter_kernel<<<(N_EDGES + 255) / 256, 256, 0, stream>>>(eidx, cursor, perm);
    edge_filter_kernel<false><<<2500, 256, 0, stream>>>(
        eidx, rbf, W1, b1, W2, b2, hbf, msg, nullptr);
    segment_reduce_kernel<<<N_NODES / 4, 256, 0, stream>>>(msg, perm, row_ptr, out);
  } else {
    hipMemsetAsync(out, 0, (size_t)N_NODES * OUT_CH * sizeof(float), stream);
    edge_filter_kernel<true><<<2500, 256, 0, stream>>>(
        eidx, rbf, W1, b1, W2, b2, hbf, nullptr, out);
  }
}